// Round 1
// baseline (3080.050 us; speedup 1.0000x reference)
//
#include <hip/hip_runtime.h>
#include <hip/hip_bf16.h>

#define CCH 64
#define NOFF 27

typedef unsigned short u16;
typedef __attribute__((ext_vector_type(8))) u16 u16x8;

static __device__ __forceinline__ u16 f2bf(float f) {
    __hip_bfloat16 h = __float2bfloat16(f);
    return *reinterpret_cast<u16*>(&h);
}
static __device__ __forceinline__ float bf2f(u16 u) {
    return __uint_as_float(((unsigned)u) << 16);
}

// Pass A: K,V projections (qkv_w rows 64..191), stored bf16 voxel-major [vox][128]
__global__ __launch_bounds__(256) void kv_kernel(
    const float* __restrict__ x, const float* __restrict__ qkv_w,
    const float* __restrict__ qkv_b, u16* __restrict__ KV, int S, int NV)
{
    int v = blockIdx.x * 256 + threadIdx.x;
    if (v >= NV) return;
    int b = v / S;
    int s = v - b * S;
    const float* xp = x + (size_t)b * CCH * S + s;
    float xv[CCH];
    #pragma unroll
    for (int c = 0; c < CCH; ++c) xv[c] = xp[(size_t)c * S];

    u16* kvp = KV + (size_t)v * 128;
    for (int ob = 0; ob < 32; ++ob) {   // 128 outputs, 4 at a time
        int o = 64 + ob * 4;
        float a0 = qkv_b[o + 0];
        float a1 = qkv_b[o + 1];
        float a2 = qkv_b[o + 2];
        float a3 = qkv_b[o + 3];
        const float* w0 = qkv_w + (size_t)o * CCH;
        #pragma unroll
        for (int c = 0; c < CCH; ++c) {
            float xc = xv[c];
            a0 += w0[c] * xc;
            a1 += w0[CCH + c] * xc;
            a2 += w0[2 * CCH + c] * xc;
            a3 += w0[3 * CCH + c] * xc;
        }
        union { u16 u[4]; uint2 v2; } pk;
        pk.u[0] = f2bf(a0); pk.u[1] = f2bf(a1);
        pk.u[2] = f2bf(a2); pk.u[3] = f2bf(a3);
        *reinterpret_cast<uint2*>(kvp + ob * 4) = pk.v2;
    }
}

// Pass B: Q projection, 27-window attention, V accumulation onto residual, out projection
__global__ __launch_bounds__(256) void attn_kernel(
    const float* __restrict__ x, const float* __restrict__ qkv_w,
    const float* __restrict__ qkv_b, const float* __restrict__ out_w,
    const float* __restrict__ out_b, const float* __restrict__ rel_pos,
    const u16* __restrict__ KV, float* __restrict__ out,
    int Dd, int Hh, int Ww, int S, int NV)
{
    int v = blockIdx.x * 256 + threadIdx.x;
    if (v >= NV) return;
    int b = v / S;
    int s = v - b * S;
    int HW = Hh * Ww;
    int d = s / HW;
    int r = s - d * HW;
    int h = r / Ww;
    int w = r - h * Ww;

    const float* xp = x + (size_t)b * CCH * S + s;
    float xv[CCH];
    #pragma unroll
    for (int c = 0; c < CCH; ++c) xv[c] = xp[(size_t)c * S];

    // Q projection (rows 0..63 of qkv_w)
    float Q[CCH];
    #pragma unroll
    for (int o = 0; o < CCH; ++o) {
        float a = qkv_b[o];
        const float* wr = qkv_w + (size_t)o * CCH;
        #pragma unroll
        for (int c = 0; c < CCH; ++c) a += wr[c] * xv[c];
        Q[o] = a;
    }

    // logits over 27 shifted windows
    float lg[NOFF];
    #pragma unroll
    for (int idx = 0; idx < NOFF; ++idx) {
        const int di = idx / 9 - 1;
        const int dj = (idx / 3) % 3 - 1;
        const int dk = idx % 3 - 1;
        bool inb = ((unsigned)(d + di) < (unsigned)Dd) &&
                   ((unsigned)(h + dj) < (unsigned)Hh) &&
                   ((unsigned)(w + dk) < (unsigned)Ww);
        float dot = 0.f;
        if (inb) {
            const u16* kp = KV + ((size_t)v + (size_t)(di * HW + dj * Ww + dk)) * 128;
            #pragma unroll
            for (int cc = 0; cc < 8; ++cc) {
                u16x8 kk = *reinterpret_cast<const u16x8*>(kp + cc * 8);
                #pragma unroll
                for (int t = 0; t < 8; ++t)
                    dot += bf2f(kk[t]) * Q[cc * 8 + t];
            }
        }
        float rdot = 0.f;
        #pragma unroll
        for (int c = 0; c < CCH; ++c) rdot += rel_pos[c * NOFF + idx] * Q[c];
        lg[idx] = 0.125f * (dot + rdot);
    }

    // softmax over 27
    float m = lg[0];
    #pragma unroll
    for (int i = 1; i < NOFF; ++i) m = fmaxf(m, lg[i]);
    float ssum = 0.f;
    #pragma unroll
    for (int i = 0; i < NOFF; ++i) { lg[i] = __expf(lg[i] - m); ssum += lg[i]; }
    float inv = 1.f / ssum;

    // V accumulation onto residual (xv becomes the accumulator)
    #pragma unroll
    for (int idx = 0; idx < NOFF; ++idx) {
        const int di = idx / 9 - 1;
        const int dj = (idx / 3) % 3 - 1;
        const int dk = idx % 3 - 1;
        bool inb = ((unsigned)(d + di) < (unsigned)Dd) &&
                   ((unsigned)(h + dj) < (unsigned)Hh) &&
                   ((unsigned)(w + dk) < (unsigned)Ww);
        if (!inb) continue;
        float a = lg[idx] * inv;
        const u16* vp = KV + ((size_t)v + (size_t)(di * HW + dj * Ww + dk)) * 128 + 64;
        #pragma unroll
        for (int cc = 0; cc < 8; ++cc) {
            u16x8 vv = *reinterpret_cast<const u16x8*>(vp + cc * 8);
            #pragma unroll
            for (int t = 0; t < 8; ++t)
                xv[cc * 8 + t] += a * bf2f(vv[t]);
        }
    }

    // out projection, 4 rows at a time (no persistent array -> no dynamic indexing)
    float* op = out + (size_t)b * CCH * S + s;
    for (int ob = 0; ob < 16; ++ob) {
        int o = ob * 4;
        float a0 = out_b[o + 0];
        float a1 = out_b[o + 1];
        float a2 = out_b[o + 2];
        float a3 = out_b[o + 3];
        const float* wr = out_w + (size_t)o * CCH;
        #pragma unroll
        for (int c = 0; c < CCH; ++c) {
            float xc = xv[c];
            a0 += wr[c] * xc;
            a1 += wr[CCH + c] * xc;
            a2 += wr[2 * CCH + c] * xc;
            a3 += wr[3 * CCH + c] * xc;
        }
        op[(size_t)(o + 0) * S] = a0;
        op[(size_t)(o + 1) * S] = a1;
        op[(size_t)(o + 2) * S] = a2;
        op[(size_t)(o + 3) * S] = a3;
    }
}

extern "C" void kernel_launch(void* const* d_in, const int* in_sizes, int n_in,
                              void* d_out, int out_size, void* d_ws, size_t ws_size,
                              hipStream_t stream) {
    const float* x       = (const float*)d_in[0];
    const float* qkv_w   = (const float*)d_in[1];
    const float* qkv_b   = (const float*)d_in[2];
    const float* out_w   = (const float*)d_in[3];
    const float* out_b   = (const float*)d_in[4];
    const float* rel_pos = (const float*)d_in[5];
    float* out = (float*)d_out;
    u16* KV = (u16*)d_ws;

    const int B = 2, D = 48, H = 96, W = 96;
    const int S = D * H * W;
    const int NV = B * S;
    const int blocks = NV / 256;

    kv_kernel<<<blocks, 256, 0, stream>>>(x, qkv_w, qkv_b, KV, S, NV);
    attn_kernel<<<blocks, 256, 0, stream>>>(x, qkv_w, qkv_b, out_w, out_b,
                                            rel_pos, KV, out, D, H, W, S, NV);
}

// Round 2
// 963.299 us; speedup vs baseline: 3.1974x; 3.1974x over previous
//
#include <hip/hip_runtime.h>
#include <hip/hip_bf16.h>

#define Sd 442368      // D*H*W
#define HWc 9216
#define Wc 96
#define Hc 96
#define Dc 48
#define BPB 1728       // blocks per batch (Sd/256)
#define NBLK 3456

typedef unsigned short u16;
typedef unsigned int u32;
typedef __attribute__((ext_vector_type(8))) short short8;
typedef __attribute__((ext_vector_type(4))) float f32x4;

static __device__ __forceinline__ u16 f2bf(float f){
    __hip_bfloat16 h = __float2bfloat16(f);
    return *reinterpret_cast<u16*>(&h);
}
static __device__ __forceinline__ u32 pk2(float a, float b){
    return ((u32)f2bf(b) << 16) | (u32)f2bf(a);
}
static __device__ __forceinline__ float bflo(u32 u){ return __uint_as_float(u << 16); }
static __device__ __forceinline__ float bfhi(u32 u){ return __uint_as_float(u & 0xffff0000u); }

// load 8 consecutive fp32 weights -> bf16 short8 fragment
static __device__ __forceinline__ short8 ldfrag_w(const float* p){
    float4 f0 = *reinterpret_cast<const float4*>(p);
    float4 f1 = *reinterpret_cast<const float4*>(p + 4);
    union { short8 s; u32 u[4]; } r;
    r.u[0] = pk2(f0.x, f0.y); r.u[1] = pk2(f0.z, f0.w);
    r.u[2] = pk2(f1.x, f1.y); r.u[3] = pk2(f1.z, f1.w);
    return r.s;
}

// ---------------- Pass A: K,V projection via MFMA, bf16 [vox][128] ----------------
__global__ __launch_bounds__(256, 2) void kv_mfma(
    const float* __restrict__ x, const float* __restrict__ qkv_w,
    const float* __restrict__ qkv_b, u16* __restrict__ KV)
{
    int bid = blockIdx.x;
    bid = (bid & 7) * (NBLK / 8) + (bid >> 3);     // XCD-contiguous swizzle (bijective: 3456%8==0)
    int batch = bid / BPB;
    int s0 = (bid - batch * BPB) * 256;
    int t = threadIdx.x, lane = t & 63, wv = t >> 6;
    int lo = lane & 15, hi = lane >> 4;
    __shared__ u16 L[256 * 72];                    // [vox][64ch + 8 pad] bf16, 36 KB

    const float* xb = x + (size_t)batch * 64 * Sd + s0;
    {   // stage this thread's voxel row (coalesced per-channel loads)
        u32 pk[32];
#pragma unroll
        for (int c = 0; c < 64; c += 2){
            float f0 = xb[(size_t)c * Sd + t];
            float f1 = xb[(size_t)(c + 1) * Sd + t];
            pk[c >> 1] = pk2(f0, f1);
        }
#pragma unroll
        for (int k = 0; k < 8; ++k){
            uint4 u; u.x = pk[k*4+0]; u.y = pk[k*4+1]; u.z = pk[k*4+2]; u.w = pk[k*4+3];
            *reinterpret_cast<uint4*>(&L[t * 72 + k * 8]) = u;
        }
    }
    __syncthreads();

    // A-fragments: qkv_w rows 64..191 (K then V), row = 64+mt*16+lo, k = kh*32+hi*8+j
    short8 af[8][2];
    f32x4  bias[8];
#pragma unroll
    for (int mt = 0; mt < 8; ++mt){
#pragma unroll
        for (int kh = 0; kh < 2; ++kh)
            af[mt][kh] = ldfrag_w(qkv_w + (size_t)(64 + mt*16 + lo) * 64 + kh*32 + hi*8);
        bias[mt] = *reinterpret_cast<const f32x4*>(qkv_b + 64 + mt*16 + hi*4);
    }

#pragma unroll
    for (int nt = 0; nt < 4; ++nt){
        int vl = wv * 64 + nt * 16 + lo;           // B col (voxel) = lane&15
        const u16* br = &L[vl * 72 + hi * 8];
        short8 b0 = *reinterpret_cast<const short8*>(br);
        short8 b1 = *reinterpret_cast<const short8*>(br + 32);
        u16* kvrow = KV + (size_t)(batch * Sd + s0 + vl) * 128 + hi * 4;
#pragma unroll
        for (int mt = 0; mt < 8; ++mt){
            f32x4 acc = bias[mt];
            acc = __builtin_amdgcn_mfma_f32_16x16x32_bf16(af[mt][0], b0, acc, 0, 0, 0);
            acc = __builtin_amdgcn_mfma_f32_16x16x32_bf16(af[mt][1], b1, acc, 0, 0, 0);
            uint2 st; st.x = pk2(acc[0], acc[1]); st.y = pk2(acc[2], acc[3]);
            *reinterpret_cast<uint2*>(kvrow + mt * 16) = st;   // out_local = mt*16+hi*4+{0..3}
        }
    }
}

// ---------------- Pass B: Q-MFMA + 27-window attention + out-proj MFMA ----------------
__global__ __launch_bounds__(256, 2) void attn_mfma(
    const float* __restrict__ x, const float* __restrict__ qkv_w,
    const float* __restrict__ qkv_b, const float* __restrict__ out_w,
    const float* __restrict__ out_b, const float* __restrict__ rel_pos,
    const u16* __restrict__ KV, float* __restrict__ out)
{
    int bid = blockIdx.x;
    bid = (bid & 7) * (NBLK / 8) + (bid >> 3);
    int batch = bid / BPB;
    int s0 = (bid - batch * BPB) * 256;
    int t = threadIdx.x, lane = t & 63, wv = t >> 6;
    int lo = lane & 15, hi = lane >> 4;
    __shared__ u16 L[256 * 72];                    // x tile -> Q tile -> attn-out tile

    const float* xb = x + (size_t)batch * 64 * Sd + s0;
    {   // stage x tile bf16
        u32 pk[32];
#pragma unroll
        for (int c = 0; c < 64; c += 2){
            float f0 = xb[(size_t)c * Sd + t];
            float f1 = xb[(size_t)(c + 1) * Sd + t];
            pk[c >> 1] = pk2(f0, f1);
        }
#pragma unroll
        for (int k = 0; k < 8; ++k){
            uint4 u; u.x = pk[k*4+0]; u.y = pk[k*4+1]; u.z = pk[k*4+2]; u.w = pk[k*4+3];
            *reinterpret_cast<uint4*>(&L[t * 72 + k * 8]) = u;
        }
    }
    __syncthreads();

    {   // Q projection via MFMA; each wave overwrites its OWN rows with Q bf16
        short8 qa[4][2];
        f32x4  qbias[4];
#pragma unroll
        for (int mt = 0; mt < 4; ++mt){
#pragma unroll
            for (int kh = 0; kh < 2; ++kh)
                qa[mt][kh] = ldfrag_w(qkv_w + (size_t)(mt*16 + lo) * 64 + kh*32 + hi*8);
            qbias[mt] = *reinterpret_cast<const f32x4*>(qkv_b + mt*16 + hi*4);
        }
#pragma unroll
        for (int nt = 0; nt < 4; ++nt){
            int vl = wv * 64 + nt * 16 + lo;
            const u16* br = &L[vl * 72 + hi * 8];
            short8 b0 = *reinterpret_cast<const short8*>(br);
            short8 b1 = *reinterpret_cast<const short8*>(br + 32);
#pragma unroll
            for (int mt = 0; mt < 4; ++mt){
                f32x4 acc = qbias[mt];
                acc = __builtin_amdgcn_mfma_f32_16x16x32_bf16(qa[mt][0], b0, acc, 0, 0, 0);
                acc = __builtin_amdgcn_mfma_f32_16x16x32_bf16(qa[mt][1], b1, acc, 0, 0, 0);
                uint2 st; st.x = pk2(acc[0], acc[1]); st.y = pk2(acc[2], acc[3]);
                *reinterpret_cast<uint2*>(&L[vl * 72 + mt * 16 + hi * 4]) = st;
            }
        }
    }
    __syncthreads();

    // per-thread: unpack own Q row
    float Q[64];
#pragma unroll
    for (int k = 0; k < 8; ++k){
        uint4 q4 = *reinterpret_cast<const uint4*>(&L[t * 72 + k * 8]);
        Q[k*8+0] = bflo(q4.x); Q[k*8+1] = bfhi(q4.x);
        Q[k*8+2] = bflo(q4.y); Q[k*8+3] = bfhi(q4.y);
        Q[k*8+4] = bflo(q4.z); Q[k*8+5] = bfhi(q4.z);
        Q[k*8+6] = bflo(q4.w); Q[k*8+7] = bfhi(q4.w);
    }

    int s = s0 + t;
    int d = s / HWc; int r = s - d * HWc; int h = r / Wc; int w = r - h * Wc;

    float lg[27];
#pragma unroll
    for (int o = 0; o < 27; ++o) lg[o] = 0.f;
    // rel_pos term: 27 independent accumulators, uniform (scalar) weight loads
#pragma unroll
    for (int c = 0; c < 64; ++c){
        float qc = Q[c];
        const float* rp = rel_pos + c * 27;
#pragma unroll
        for (int o = 0; o < 27; ++o) lg[o] += rp[o] * qc;
    }

    const u16* kvbase = KV + (size_t)(batch * Sd + s) * 128;
#pragma unroll
    for (int o = 0; o < 27; ++o){
        const int di = o / 9 - 1, dj = (o / 3) % 3 - 1, dk = o % 3 - 1;
        bool inb = ((unsigned)(d + di) < (unsigned)Dc) &&
                   ((unsigned)(h + dj) < (unsigned)Hc) &&
                   ((unsigned)(w + dk) < (unsigned)Wc);
        if (inb){
            const u16* kp = kvbase + (ptrdiff_t)(di * HWc + dj * Wc + dk) * 128;
            float d0 = 0.f, d1 = 0.f, d2 = 0.f, d3 = 0.f;
#pragma unroll
            for (int k = 0; k < 8; ++k){
                uint4 kk = *reinterpret_cast<const uint4*>(kp + k * 8);
                d0 += bflo(kk.x) * Q[k*8+0]; d1 += bfhi(kk.x) * Q[k*8+1];
                d2 += bflo(kk.y) * Q[k*8+2]; d3 += bfhi(kk.y) * Q[k*8+3];
                d0 += bflo(kk.z) * Q[k*8+4]; d1 += bfhi(kk.z) * Q[k*8+5];
                d2 += bflo(kk.w) * Q[k*8+6]; d3 += bfhi(kk.w) * Q[k*8+7];
            }
            lg[o] += (d0 + d1) + (d2 + d3);
        }
        lg[o] *= 0.125f;
    }

    // softmax over 27
    float m = lg[0];
#pragma unroll
    for (int o = 1; o < 27; ++o) m = fmaxf(m, lg[o]);
    float ssum = 0.f;
#pragma unroll
    for (int o = 0; o < 27; ++o){ lg[o] = __expf(lg[o] - m); ssum += lg[o]; }
    float inv = 1.f / ssum;

    // V accumulation (Q registers dead -> acc reuses the budget)
    float acc[64];
#pragma unroll
    for (int c = 0; c < 64; ++c) acc[c] = 0.f;
#pragma unroll
    for (int o = 0; o < 27; ++o){
        const int di = o / 9 - 1, dj = (o / 3) % 3 - 1, dk = o % 3 - 1;
        bool inb = ((unsigned)(d + di) < (unsigned)Dc) &&
                   ((unsigned)(h + dj) < (unsigned)Hc) &&
                   ((unsigned)(w + dk) < (unsigned)Wc);
        if (!inb) continue;
        float a = lg[o] * inv;
        const u16* vp = kvbase + (ptrdiff_t)(di * HWc + dj * Wc + dk) * 128 + 64;
#pragma unroll
        for (int k = 0; k < 8; ++k){
            uint4 vv = *reinterpret_cast<const uint4*>(vp + k * 8);
            acc[k*8+0] += a * bflo(vv.x); acc[k*8+1] += a * bfhi(vv.x);
            acc[k*8+2] += a * bflo(vv.y); acc[k*8+3] += a * bfhi(vv.y);
            acc[k*8+4] += a * bflo(vv.z); acc[k*8+5] += a * bfhi(vv.z);
            acc[k*8+6] += a * bflo(vv.w); acc[k*8+7] += a * bfhi(vv.w);
        }
    }
    // residual (fp32, re-read coalesced)
#pragma unroll
    for (int c = 0; c < 64; ++c) acc[c] += xb[(size_t)c * Sd + t];

    __syncthreads();
    // write attn-out rows bf16 into L
#pragma unroll
    for (int k = 0; k < 8; ++k){
        uint4 u;
        u.x = pk2(acc[k*8+0], acc[k*8+1]); u.y = pk2(acc[k*8+2], acc[k*8+3]);
        u.z = pk2(acc[k*8+4], acc[k*8+5]); u.w = pk2(acc[k*8+6], acc[k*8+7]);
        *reinterpret_cast<uint4*>(&L[t * 72 + k * 8]) = u;
    }
    __syncthreads();

    {   // out projection via MFMA, fp32 channel-major stores
        short8 oa[4][2];
        f32x4  obias[4];
#pragma unroll
        for (int mt = 0; mt < 4; ++mt){
#pragma unroll
            for (int kh = 0; kh < 2; ++kh)
                oa[mt][kh] = ldfrag_w(out_w + (size_t)(mt*16 + lo) * 64 + kh*32 + hi*8);
            obias[mt] = *reinterpret_cast<const f32x4*>(out_b + mt*16 + hi*4);
        }
#pragma unroll
        for (int nt = 0; nt < 4; ++nt){
            int vl = wv * 64 + nt * 16 + lo;
            const u16* br = &L[vl * 72 + hi * 8];
            short8 b0 = *reinterpret_cast<const short8*>(br);
            short8 b1 = *reinterpret_cast<const short8*>(br + 32);
#pragma unroll
            for (int mt = 0; mt < 4; ++mt){
                f32x4 a4 = obias[mt];
                a4 = __builtin_amdgcn_mfma_f32_16x16x32_bf16(oa[mt][0], b0, a4, 0, 0, 0);
                a4 = __builtin_amdgcn_mfma_f32_16x16x32_bf16(oa[mt][1], b1, a4, 0, 0, 0);
                float* op = out + ((size_t)batch * 64 + mt*16 + hi*4) * Sd + (s0 + vl);
                op[0]          = a4[0];
                op[(size_t)Sd]     = a4[1];
                op[(size_t)2*Sd]   = a4[2];
                op[(size_t)3*Sd]   = a4[3];
            }
        }
    }
}

extern "C" void kernel_launch(void* const* d_in, const int* in_sizes, int n_in,
                              void* d_out, int out_size, void* d_ws, size_t ws_size,
                              hipStream_t stream) {
    const float* x       = (const float*)d_in[0];
    const float* qkv_w   = (const float*)d_in[1];
    const float* qkv_b   = (const float*)d_in[2];
    const float* out_w   = (const float*)d_in[3];
    const float* out_b   = (const float*)d_in[4];
    const float* rel_pos = (const float*)d_in[5];
    float* out = (float*)d_out;
    u16* KV = (u16*)d_ws;   // 884736 * 128 * 2B = 216 MB

    kv_mfma<<<NBLK, 256, 0, stream>>>(x, qkv_w, qkv_b, KV);
    attn_mfma<<<NBLK, 256, 0, stream>>>(x, qkv_w, qkv_b, out_w, out_b,
                                        rel_pos, KV, out);
}

// Round 3
// 689.967 us; speedup vs baseline: 4.4641x; 1.3962x over previous
//
#include <hip/hip_runtime.h>
#include <hip/hip_bf16.h>

#define Sd 442368      // D*H*W
#define HWc 9216
#define Wc 96
#define Hc 96
#define Dc 48

typedef unsigned short u16;
typedef unsigned int u32;
typedef __attribute__((ext_vector_type(8))) short short8;
typedef __attribute__((ext_vector_type(4))) float f32x4;

static __device__ __forceinline__ u16 f2bf(float f){
    __hip_bfloat16 h = __float2bfloat16(f);
    return *reinterpret_cast<u16*>(&h);
}
static __device__ __forceinline__ u32 pk2(float a, float b){
    return ((u32)f2bf(b) << 16) | (u32)f2bf(a);
}
static __device__ __forceinline__ float bflo(u32 u){ return __uint_as_float(u << 16); }
static __device__ __forceinline__ float bfhi(u32 u){ return __uint_as_float(u & 0xffff0000u); }

static __device__ __forceinline__ short8 ldfrag_w(const float* p){
    float4 f0 = *reinterpret_cast<const float4*>(p);
    float4 f1 = *reinterpret_cast<const float4*>(p + 4);
    union { short8 s; u32 u[4]; } r;
    r.u[0] = pk2(f0.x, f0.y); r.u[1] = pk2(f0.z, f0.w);
    r.u[2] = pk2(f1.x, f1.y); r.u[3] = pk2(f1.z, f1.w);
    return r.s;
}

// ---------------- Pass A: K,V projection via MFMA, bf16 [vox][128] ----------------
#define NBLK_A 3456
__global__ __launch_bounds__(256, 2) void kv_mfma(
    const float* __restrict__ x, const float* __restrict__ qkv_w,
    const float* __restrict__ qkv_b, u16* __restrict__ KV)
{
    int bid = blockIdx.x;
    bid = (bid & 7) * (NBLK_A / 8) + (bid >> 3);
    int batch = bid / (NBLK_A / 2);
    int s0 = (bid - batch * (NBLK_A / 2)) * 256;
    int t = threadIdx.x, lane = t & 63, wv = t >> 6;
    int lo = lane & 15, hi = lane >> 4;
    __shared__ u16 L[256 * 72];

    const float* xb = x + (size_t)batch * 64 * Sd + s0;
    {
        u32 pk[32];
#pragma unroll
        for (int c = 0; c < 64; c += 2){
            float f0 = xb[(size_t)c * Sd + t];
            float f1 = xb[(size_t)(c + 1) * Sd + t];
            pk[c >> 1] = pk2(f0, f1);
        }
#pragma unroll
        for (int k = 0; k < 8; ++k){
            uint4 u; u.x = pk[k*4+0]; u.y = pk[k*4+1]; u.z = pk[k*4+2]; u.w = pk[k*4+3];
            *reinterpret_cast<uint4*>(&L[t * 72 + k * 8]) = u;
        }
    }
    __syncthreads();

    short8 af[8][2];
    f32x4  bias[8];
#pragma unroll
    for (int mt = 0; mt < 8; ++mt){
#pragma unroll
        for (int kh = 0; kh < 2; ++kh)
            af[mt][kh] = ldfrag_w(qkv_w + (size_t)(64 + mt*16 + lo) * 64 + kh*32 + hi*8);
        bias[mt] = *reinterpret_cast<const f32x4*>(qkv_b + 64 + mt*16 + hi*4);
    }

#pragma unroll
    for (int nt = 0; nt < 4; ++nt){
        int vl = wv * 64 + nt * 16 + lo;
        const u16* br = &L[vl * 72 + hi * 8];
        short8 b0 = *reinterpret_cast<const short8*>(br);
        short8 b1 = *reinterpret_cast<const short8*>(br + 32);
        u16* kvrow = KV + (size_t)(batch * Sd + s0 + vl) * 128 + hi * 4;
#pragma unroll
        for (int mt = 0; mt < 8; ++mt){
            f32x4 acc = bias[mt];
            acc = __builtin_amdgcn_mfma_f32_16x16x32_bf16(af[mt][0], b0, acc, 0, 0, 0);
            acc = __builtin_amdgcn_mfma_f32_16x16x32_bf16(af[mt][1], b1, acc, 0, 0, 0);
            uint2 st; st.x = pk2(acc[0], acc[1]); st.y = pk2(acc[2], acc[3]);
            *reinterpret_cast<uint2*>(kvrow + mt * 16) = st;
        }
    }
}

// ---------------- Pass B: 2 threads/voxel attention ----------------
#define NBLK_B 6912
__global__ __launch_bounds__(256, 4) void attn_mfma2(
    const float* __restrict__ x, const float* __restrict__ qkv_w,
    const float* __restrict__ qkv_b, const float* __restrict__ out_w,
    const float* __restrict__ out_b, const float* __restrict__ rel_pos,
    const u16* __restrict__ KV, float* __restrict__ out)
{
    int bid = blockIdx.x;
    bid = (bid & 7) * (NBLK_B / 8) + (bid >> 3);
    int batch = bid / (NBLK_B / 2);
    int s0 = (bid - batch * (NBLK_B / 2)) * 128;
    int t = threadIdx.x, lane = t & 63, wv = t >> 6;
    int lo = lane & 15, hi = lane >> 4;
    int vt = t >> 1, half = t & 1;

    __shared__ u16 Lx[128 * 72];   // x bf16 tile -> later fp32 rel-logits
    __shared__ u16 Lq[128 * 72];   // Q bf16 tile -> later attn-out bf16 tile
    float* Lr = reinterpret_cast<float*>(Lx);

    const float* xb = x + (size_t)batch * 64 * Sd + s0;
    {   // stage own 32 channels of voxel vt
        u32 pk[16];
#pragma unroll
        for (int c2 = 0; c2 < 32; c2 += 2){
            float f0 = xb[(size_t)(half*32 + c2) * Sd + vt];
            float f1 = xb[(size_t)(half*32 + c2 + 1) * Sd + vt];
            pk[c2 >> 1] = pk2(f0, f1);
        }
#pragma unroll
        for (int k = 0; k < 4; ++k){
            uint4 u; u.x = pk[k*4+0]; u.y = pk[k*4+1]; u.z = pk[k*4+2]; u.w = pk[k*4+3];
            *reinterpret_cast<uint4*>(&Lx[vt * 72 + half * 32 + k * 8]) = u;
        }
    }
    __syncthreads();

    {   // Q-projection MFMA -> Lq
        short8 qa[4][2];
        f32x4  qbias[4];
#pragma unroll
        for (int mt = 0; mt < 4; ++mt){
#pragma unroll
            for (int kh = 0; kh < 2; ++kh)
                qa[mt][kh] = ldfrag_w(qkv_w + (size_t)(mt*16 + lo) * 64 + kh*32 + hi*8);
            qbias[mt] = *reinterpret_cast<const f32x4*>(qkv_b + mt*16 + hi*4);
        }
#pragma unroll
        for (int nt = 0; nt < 2; ++nt){
            int vl = wv * 32 + nt * 16 + lo;
            const u16* br = &Lx[vl * 72 + hi * 8];
            short8 b0 = *reinterpret_cast<const short8*>(br);
            short8 b1 = *reinterpret_cast<const short8*>(br + 32);
#pragma unroll
            for (int mt = 0; mt < 4; ++mt){
                f32x4 acc = qbias[mt];
                acc = __builtin_amdgcn_mfma_f32_16x16x32_bf16(qa[mt][0], b0, acc, 0, 0, 0);
                acc = __builtin_amdgcn_mfma_f32_16x16x32_bf16(qa[mt][1], b1, acc, 0, 0, 0);
                uint2 st; st.x = pk2(acc[0], acc[1]); st.y = pk2(acc[2], acc[3]);
                *reinterpret_cast<uint2*>(&Lq[vl * 72 + mt * 16 + hi * 4]) = st;
            }
        }
    }
    __syncthreads();

    // capture residual (own x half) and Q (own half) into registers
    float acc[32], Q[32];
    {
        const u16* xr = &Lx[vt * 72 + half * 32];
        const u16* qr = &Lq[vt * 72 + half * 32];
#pragma unroll
        for (int k = 0; k < 4; ++k){
            uint4 xa = *reinterpret_cast<const uint4*>(xr + k * 8);
            uint4 qa = *reinterpret_cast<const uint4*>(qr + k * 8);
            acc[k*8+0] = bflo(xa.x); acc[k*8+1] = bfhi(xa.x);
            acc[k*8+2] = bflo(xa.y); acc[k*8+3] = bfhi(xa.y);
            acc[k*8+4] = bflo(xa.z); acc[k*8+5] = bfhi(xa.z);
            acc[k*8+6] = bflo(xa.w); acc[k*8+7] = bfhi(xa.w);
            Q[k*8+0] = bflo(qa.x); Q[k*8+1] = bfhi(qa.x);
            Q[k*8+2] = bflo(qa.y); Q[k*8+3] = bfhi(qa.y);
            Q[k*8+4] = bflo(qa.z); Q[k*8+5] = bfhi(qa.z);
            Q[k*8+6] = bflo(qa.w); Q[k*8+7] = bfhi(qa.w);
        }
    }
    __syncthreads();   // everyone done reading Lx; rel-MFMA may overwrite it

    {   // rel-logits MFMA: R (27x64, zero-padded to 32) x Q-tile -> Lr fp32 [128][29]
        short8 ra[2][2];
#pragma unroll
        for (int mt = 0; mt < 2; ++mt){
            int o = mt * 16 + lo;
#pragma unroll
            for (int kh = 0; kh < 2; ++kh){
                float f[8];
#pragma unroll
                for (int j = 0; j < 8; ++j){
                    int k = kh * 32 + hi * 8 + j;
                    f[j] = (o < 27) ? rel_pos[k * 27 + o] : 0.f;
                }
                union { short8 s; u32 u[4]; } r;
                r.u[0] = pk2(f[0], f[1]); r.u[1] = pk2(f[2], f[3]);
                r.u[2] = pk2(f[4], f[5]); r.u[3] = pk2(f[6], f[7]);
                ra[mt][kh] = r.s;
            }
        }
#pragma unroll
        for (int nt = 0; nt < 2; ++nt){
            int vl = wv * 32 + nt * 16 + lo;
            const u16* br = &Lq[vl * 72 + hi * 8];
            short8 b0 = *reinterpret_cast<const short8*>(br);
            short8 b1 = *reinterpret_cast<const short8*>(br + 32);
            f32x4 a0 = {0.f, 0.f, 0.f, 0.f};
            f32x4 a1 = {0.f, 0.f, 0.f, 0.f};
            a0 = __builtin_amdgcn_mfma_f32_16x16x32_bf16(ra[0][0], b0, a0, 0, 0, 0);
            a0 = __builtin_amdgcn_mfma_f32_16x16x32_bf16(ra[0][1], b1, a0, 0, 0, 0);
            a1 = __builtin_amdgcn_mfma_f32_16x16x32_bf16(ra[1][0], b0, a1, 0, 0, 0);
            a1 = __builtin_amdgcn_mfma_f32_16x16x32_bf16(ra[1][1], b1, a1, 0, 0, 0);
#pragma unroll
            for (int j = 0; j < 4; ++j)
                Lr[vl * 29 + hi * 4 + j] = a0[j];
#pragma unroll
            for (int j = 0; j < 4; ++j){
                int row = 16 + hi * 4 + j;
                if (row < 27) Lr[vl * 29 + row] = a1[j];
            }
        }
    }
    __syncthreads();

    int s = s0 + vt;
    int d = s / HWc; int r = s - d * HWc; int h = r / Wc; int w = r - h * Wc;
    const u16* kvb = KV + ((size_t)batch * Sd + s) * 128 + half * 32;

    float lg[27];
#pragma unroll
    for (int o = 0; o < 27; ++o){
        const int di = o / 9 - 1, dj = (o / 3) % 3 - 1, dk = o % 3 - 1;
        bool inb = ((unsigned)(d + di) < (unsigned)Dc) &&
                   ((unsigned)(h + dj) < (unsigned)Hc) &&
                   ((unsigned)(w + dk) < (unsigned)Wc);
        float dsum = 0.f;
        if (inb){
            const u16* kp = kvb + (ptrdiff_t)(di * HWc + dj * Wc + dk) * 128;
            float d0 = 0.f, d1 = 0.f, d2 = 0.f, d3 = 0.f;
#pragma unroll
            for (int k = 0; k < 4; ++k){
                uint4 kk = *reinterpret_cast<const uint4*>(kp + k * 8);
                d0 += bflo(kk.x) * Q[k*8+0]; d1 += bfhi(kk.x) * Q[k*8+1];
                d2 += bflo(kk.y) * Q[k*8+2]; d3 += bfhi(kk.y) * Q[k*8+3];
                d0 += bflo(kk.z) * Q[k*8+4]; d1 += bfhi(kk.z) * Q[k*8+5];
                d2 += bflo(kk.w) * Q[k*8+6]; d3 += bfhi(kk.w) * Q[k*8+7];
            }
            dsum = (d0 + d1) + (d2 + d3);
        }
        lg[o] = dsum;
    }
    // pair-sum + rel + scale
#pragma unroll
    for (int o = 0; o < 27; ++o){
        float other = __shfl_xor(lg[o], 1);
        lg[o] = 0.125f * (lg[o] + other + Lr[vt * 29 + o]);
    }

    float m = lg[0];
#pragma unroll
    for (int o = 1; o < 27; ++o) m = fmaxf(m, lg[o]);
    float ssum = 0.f;
#pragma unroll
    for (int o = 0; o < 27; ++o){ lg[o] = __expf(lg[o] - m); ssum += lg[o]; }
    float inv = 1.f / ssum;

#pragma unroll
    for (int o = 0; o < 27; ++o){
        const int di = o / 9 - 1, dj = (o / 3) % 3 - 1, dk = o % 3 - 1;
        bool inb = ((unsigned)(d + di) < (unsigned)Dc) &&
                   ((unsigned)(h + dj) < (unsigned)Hc) &&
                   ((unsigned)(w + dk) < (unsigned)Wc);
        if (!inb) continue;
        float a = lg[o] * inv;
        const u16* vp = kvb + (ptrdiff_t)(di * HWc + dj * Wc + dk) * 128 + 64;
#pragma unroll
        for (int k = 0; k < 4; ++k){
            uint4 vv = *reinterpret_cast<const uint4*>(vp + k * 8);
            acc[k*8+0] += a * bflo(vv.x); acc[k*8+1] += a * bfhi(vv.x);
            acc[k*8+2] += a * bflo(vv.y); acc[k*8+3] += a * bfhi(vv.y);
            acc[k*8+4] += a * bflo(vv.z); acc[k*8+5] += a * bfhi(vv.z);
            acc[k*8+6] += a * bflo(vv.w); acc[k*8+7] += a * bfhi(vv.w);
        }
    }

    // write attn-out (own half) bf16 into Lq
#pragma unroll
    for (int k = 0; k < 4; ++k){
        uint4 u;
        u.x = pk2(acc[k*8+0], acc[k*8+1]); u.y = pk2(acc[k*8+2], acc[k*8+3]);
        u.z = pk2(acc[k*8+4], acc[k*8+5]); u.w = pk2(acc[k*8+6], acc[k*8+7]);
        *reinterpret_cast<uint4*>(&Lq[vt * 72 + half * 32 + k * 8]) = u;
    }
    __syncthreads();

    {   // out-projection MFMA -> fp32 stores
        short8 oa[4][2];
        f32x4  obias[4];
#pragma unroll
        for (int mt = 0; mt < 4; ++mt){
#pragma unroll
            for (int kh = 0; kh < 2; ++kh)
                oa[mt][kh] = ldfrag_w(out_w + (size_t)(mt*16 + lo) * 64 + kh*32 + hi*8);
            obias[mt] = *reinterpret_cast<const f32x4*>(out_b + mt*16 + hi*4);
        }
#pragma unroll
        for (int nt = 0; nt < 2; ++nt){
            int vl = wv * 32 + nt * 16 + lo;
            const u16* br = &Lq[vl * 72 + hi * 8];
            short8 b0 = *reinterpret_cast<const short8*>(br);
            short8 b1 = *reinterpret_cast<const short8*>(br + 32);
#pragma unroll
            for (int mt = 0; mt < 4; ++mt){
                f32x4 a4 = obias[mt];
                a4 = __builtin_amdgcn_mfma_f32_16x16x32_bf16(oa[mt][0], b0, a4, 0, 0, 0);
                a4 = __builtin_amdgcn_mfma_f32_16x16x32_bf16(oa[mt][1], b1, a4, 0, 0, 0);
                float* op = out + ((size_t)batch * 64 + mt*16 + hi*4) * Sd + (s0 + vl);
                op[0]              = a4[0];
                op[(size_t)Sd]     = a4[1];
                op[(size_t)2*Sd]   = a4[2];
                op[(size_t)3*Sd]   = a4[3];
            }
        }
    }
}

extern "C" void kernel_launch(void* const* d_in, const int* in_sizes, int n_in,
                              void* d_out, int out_size, void* d_ws, size_t ws_size,
                              hipStream_t stream) {
    const float* x       = (const float*)d_in[0];
    const float* qkv_w   = (const float*)d_in[1];
    const float* qkv_b   = (const float*)d_in[2];
    const float* out_w   = (const float*)d_in[3];
    const float* out_b   = (const float*)d_in[4];
    const float* rel_pos = (const float*)d_in[5];
    float* out = (float*)d_out;
    u16* KV = (u16*)d_ws;   // 884736 * 128 * 2B = 216 MB

    kv_mfma<<<NBLK_A, 256, 0, stream>>>(x, qkv_w, qkv_b, KV);
    attn_mfma2<<<NBLK_B, 256, 0, stream>>>(x, qkv_w, qkv_b, out_w, out_b,
                                           rel_pos, KV, out);
}